// Round 9
// baseline (208.727 us; speedup 1.0000x reference)
//
#include <hip/hip_runtime.h>
#include <hip/hip_bf16.h>

typedef unsigned short ushort_t;
typedef unsigned int uint_t;
typedef __attribute__((ext_vector_type(8))) short short8v;
typedef __attribute__((ext_vector_type(4))) float f32x4;

__device__ __forceinline__ float bf2f(ushort_t u) {
    union { uint_t u; float f; } v; v.u = (uint_t)u << 16; return v.f;
}
__device__ __forceinline__ ushort_t f2bf(float f) {
    __hip_bfloat16 h = __float2bfloat16(f);   // RNE; compiler fuses pairs to v_cvt_pk_bf16_f32
    return *reinterpret_cast<ushort_t*>(&h);
}

#define MFMA(A,B,C) __builtin_amdgcn_mfma_f32_16x16x32_bf16(A, B, C, 0, 0, 0)

// split 8 fp32 -> bf16 hi + bf16 lo fragments (in-register)
__device__ __forceinline__ void split8(float4 f0, float4 f1, short8v& h8, short8v& l8) {
    float v[8] = {f0.x, f0.y, f0.z, f0.w, f1.x, f1.y, f1.z, f1.w};
    union { short8v v; ushort_t s[8]; } H, L;
    #pragma unroll
    for (int e = 0; e < 8; ++e) {
        ushort_t h = f2bf(v[e]);
        H.s[e] = h;
        L.s[e] = f2bf(v[e] - bf2f(h));
    }
    h8 = H.v; l8 = L.v;
}

// ---------------- Kernel 1 v2: pointwise conv + BN fold — direct-from-global MFMA ----
// No LDS, no barriers. Fragments loaded straight from global:
//   B (x): lane needs pixel px = hw0+16w+lr, channels 32kc+8half+e -> wave-coalesced 64B runs.
//   A (w_in): lane needs row o = 16ot+lr, same channel chunks -> 2 float4, L2-hot.
__global__ __launch_bounds__(256, 4) void k1_pwbn_direct(
    const float* __restrict__ x, const float* __restrict__ w_in, const float* __restrict__ b_in,
    const float* __restrict__ gamma, const float* __restrict__ beta,
    const float* __restrict__ mean, const float* __restrict__ var,
    ushort_t* __restrict__ xbn)
{
    int tid = threadIdx.x;
    int b   = blockIdx.x >> 10;
    int hw0 = (blockIdx.x & 1023) << 6;
    const float* xb = x + ((size_t)b << 22);

    int w = tid >> 6, l = tid & 63;
    int half = l >> 4, lr = l & 15;
    int k0 = half * 8;
    int px = hw0 + 16 * w + lr;

    // B fragments from x (hi/lo split)
    short8v bh[2], bl[2];
    #pragma unroll
    for (int kc = 0; kc < 2; ++kc) {
        union { short8v v; ushort_t s[8]; } H, L;
        #pragma unroll
        for (int e = 0; e < 8; ++e) {
            float xv = xb[((32 * kc + k0 + e) << 16) + px];
            ushort_t h = f2bf(xv);
            H.s[e] = h;
            L.s[e] = f2bf(xv - bf2f(h));
        }
        bh[kc] = H.v; bl[kc] = L.v;
    }

    ushort_t* xp = xbn + ((size_t)(b * 65536 + px) << 6);
    #pragma unroll
    for (int ot = 0; ot < 4; ++ot) {
        // A fragments from w_in row o (scaled), hi/lo split
        int o = 16 * ot + lr;
        float sc = gamma[o] * rsqrtf(var[o] + 1e-5f);
        short8v ah[2], al[2];
        #pragma unroll
        for (int kc = 0; kc < 2; ++kc) {
            float4 fa = *(const float4*)(w_in + o * 64 + 32 * kc + k0);
            float4 fb = *(const float4*)(w_in + o * 64 + 32 * kc + k0 + 4);
            float vv[8] = {fa.x, fa.y, fa.z, fa.w, fb.x, fb.y, fb.z, fb.w};
            union { short8v v; ushort_t s[8]; } H, L;
            #pragma unroll
            for (int e = 0; e < 8; ++e) {
                float wv = vv[e] * sc;
                ushort_t h = f2bf(wv);
                H.s[e] = h;
                L.s[e] = f2bf(wv - bf2f(h));
            }
            ah[kc] = H.v; al[kc] = L.v;
        }

        f32x4 acc = {0.f, 0.f, 0.f, 0.f};
        #pragma unroll
        for (int kc = 0; kc < 2; ++kc) {
            acc = MFMA(ah[kc], bh[kc], acc);
            acc = MFMA(ah[kc], bl[kc], acc);
            acc = MFMA(al[kc], bh[kc], acc);
        }
        // C rows: o = 16ot + 4half + rr ; col = px (lane)
        int o0 = 16 * ot + 4 * half;
        float4 g4 = *(const float4*)(gamma + o0);
        float4 v4 = *(const float4*)(var + o0);
        float4 bi4 = *(const float4*)(b_in + o0);
        float4 mn4 = *(const float4*)(mean + o0);
        float4 bt4 = *(const float4*)(beta + o0);
        float gv[4] = {g4.x, g4.y, g4.z, g4.w};
        float vv2[4] = {v4.x, v4.y, v4.z, v4.w};
        float bi[4] = {bi4.x, bi4.y, bi4.z, bi4.w};
        float mn[4] = {mn4.x, mn4.y, mn4.z, mn4.w};
        float bt[4] = {bt4.x, bt4.y, bt4.z, bt4.w};
        ushort_t hs[4];
        #pragma unroll
        for (int rr = 0; rr < 4; ++rr) {
            float inv = gv[rr] * rsqrtf(vv2[rr] + 1e-5f);
            float bef = (bi[rr] - mn[rr]) * inv + bt[rr];
            hs[rr] = f2bf(acc[rr] + bef);
        }
        *(uint2*)(xp + o0) = make_uint2((uint_t)hs[0] | ((uint_t)hs[1] << 16),
                                        (uint_t)hs[2] | ((uint_t)hs[3] << 16));
    }
}

// ---------------- Kernel 2 v5: register-softmax MFMA attention, direct G4 store ----
// 4 barriers. LDS: g->VWT, V->P~, qh, ql, red, red2 (38.9 KB). G4 writes straight to out.
#define K4_G    0
#define K4_V    9216
#define K4_QH   18432
#define K4_QL   27648
#define K4_RED  36864
#define K4_RED2 37888
#define K4_TOT  38912

__global__ __launch_bounds__(256, 4) void k2_attn_v5(
    const ushort_t* __restrict__ xbn,
    const float* __restrict__ w_mask, const float* __restrict__ b_mask,
    const float* __restrict__ w_out,  const float* __restrict__ b_out,
    float* __restrict__ out)
{
    __shared__ char smem[K4_TOT];
    short* gb   = (short*)(smem + K4_G);
    short* vb   = (short*)(smem + K4_V);
    short* qhb  = (short*)(smem + K4_QH);
    short* qlb  = (short*)(smem + K4_QL);
    short* vwt  = (short*)(smem + K4_G);    // aliases g after G1
    short* pt   = (short*)(smem + K4_V);    // aliases V after G2
    float* red  = (float*)(smem + K4_RED);  // [t][w] max partials
    float* red2 = (float*)(smem + K4_RED2); // [t][w] sum partials

    int tid = threadIdx.x;
    int wid = blockIdx.x;
    int b = wid >> 10, i = (wid >> 5) & 31, j = wid & 31;
    const ushort_t* xb = xbn + ((size_t)b << 22);

    int w = tid >> 6, l = tid & 63;
    int half = l >> 4, lr = l & 15;
    int mrow = (16 * w + lr) * 72;
    int kc0 = half * 8, kc1 = 32 + half * 8;

    // ---- weight prefetch (per-lane own row; latency hidden behind staging + G1) ----
    const float* wmp = w_mask + (16 * w + lr) * 64;
    const float* wop = w_out  + (16 * w + lr) * 64;
    float4 wmA = *(const float4*)(wmp + kc0), wmB = *(const float4*)(wmp + kc0 + 4);
    float4 wmC = *(const float4*)(wmp + kc1), wmD = *(const float4*)(wmp + kc1 + 4);
    float4 woA = *(const float4*)(wop + kc0), woB = *(const float4*)(wop + kc0 + 4);
    float4 woC = *(const float4*)(wop + kc1), woD = *(const float4*)(wop + kc1 + 4);

    // ---- stage g, V (raw bf16 row copies, pitch 72) ----
    {
        int t = tid >> 2, seg = tid & 3;
        int r = t & 7, s = t >> 3;
        int pr = i * 8 + 2 * r; if (pr >= 256) pr -= 8;
        int pc = j * 8 + 2 * s; if (pc >= 256) pc -= 8;
        const ushort_t* src = xb + (((size_t)((pr << 8) | pc)) << 6) + seg * 16;
        *(int4*)(gb + t * 72 + seg * 16)     = *(const int4*)src;
        *(int4*)(gb + t * 72 + seg * 16 + 8) = *(const int4*)(src + 8);
        int vr = i * 8 + (t >> 3), vc = j * 8 + (t & 7);
        const ushort_t* vsrc = xb + (((size_t)((vr << 8) | vc)) << 6) + seg * 16;
        *(int4*)(vb + t * 72 + seg * 16)     = *(const int4*)vsrc;
        *(int4*)(vb + t * 72 + seg * 16 + 8) = *(const int4*)(vsrc + 8);
    }
    __syncthreads();                                   // --- barrier 1

    // ---- G1 (m-split): q = g @ wm^T + b_mask ----
    {
        short8v amh0, aml0, amh1, aml1;
        split8(wmA, wmB, amh0, aml0);
        split8(wmC, wmD, amh1, aml1);
        float4 bm = *(const float4*)(b_mask + 16 * w + half * 4);
        float bmv[4] = {bm.x, bm.y, bm.z, bm.w};
        #pragma unroll
        for (int n = 0; n < 4; ++n) {
            int nrow = (16 * n + lr) * 72;
            short8v bg0 = *(short8v*)(gb + nrow + kc0);
            short8v bg1 = *(short8v*)(gb + nrow + kc1);
            f32x4 acc = {0.f, 0.f, 0.f, 0.f};
            acc = MFMA(amh0, bg0, acc);
            acc = MFMA(amh1, bg1, acc);
            acc = MFMA(aml0, bg0, acc);
            acc = MFMA(aml1, bg1, acc);
            ushort_t hs[4], ls[4];
            #pragma unroll
            for (int rr = 0; rr < 4; ++rr) {
                float qv = acc[rr] + bmv[rr];
                hs[rr] = f2bf(qv);
                ls[rr] = f2bf(qv - bf2f(hs[rr]));
            }
            int qoff = (16 * n + lr) * 72 + 16 * w + half * 4;   // qT[t][o]
            *(uint2*)(qhb + qoff) = make_uint2((uint_t)hs[0] | ((uint_t)hs[1] << 16),
                                               (uint_t)hs[2] | ((uint_t)hs[3] << 16));
            *(uint2*)(qlb + qoff) = make_uint2((uint_t)ls[0] | ((uint_t)ls[1] << 16),
                                               (uint_t)ls[2] | ((uint_t)ls[3] << 16));
        }
    }
    __syncthreads();                                   // --- barrier 2

    // ---- G2 (n-split): VWT[o][u] = (V @ wo^T)^T ----
    {
        short8v bh0, bl0, bh1, bl1;
        split8(woA, woB, bh0, bl0);
        split8(woC, woD, bh1, bl1);
        #pragma unroll
        for (int mm = 0; mm < 4; ++mm) {
            int arow = (16 * mm + lr) * 72;
            short8v av0 = *(short8v*)(vb + arow + kc0);
            short8v av1 = *(short8v*)(vb + arow + kc1);
            f32x4 acc = {0.f, 0.f, 0.f, 0.f};
            acc = MFMA(av0, bh0, acc);
            acc = MFMA(av1, bh1, acc);
            acc = MFMA(av0, bl0, acc);
            acc = MFMA(av1, bl1, acc);
            ushort_t hs[4];
            #pragma unroll
            for (int rr = 0; rr < 4; ++rr) hs[rr] = f2bf(acc[rr]);
            int voff = (16 * w + lr) * 72 + 16 * mm + 4 * half;  // VWT[o][u]
            *(uint2*)(vwt + voff) = make_uint2((uint_t)hs[0] | ((uint_t)hs[1] << 16),
                                               (uint_t)hs[2] | ((uint_t)hs[3] << 16));
        }
    }
    // ---- G3 (m-split, same phase): S tiles stay in REGISTERS ----
    f32x4 sreg[4];
    {
        short8v ah0 = *(short8v*)(qhb + mrow + kc0);
        short8v ah1 = *(short8v*)(qhb + mrow + kc1);
        short8v al0 = *(short8v*)(qlb + mrow + kc0);
        short8v al1 = *(short8v*)(qlb + mrow + kc1);
        #pragma unroll
        for (int n = 0; n < 4; ++n) {
            int nrow = (16 * n + lr) * 72;
            short8v bh0 = *(short8v*)(qhb + nrow + kc0);
            short8v bh1 = *(short8v*)(qhb + nrow + kc1);
            short8v bl0 = *(short8v*)(qlb + nrow + kc0);
            short8v bl1 = *(short8v*)(qlb + nrow + kc1);
            f32x4 acc = {0.f, 0.f, 0.f, 0.f};
            acc = MFMA(ah0, bh0, acc);
            acc = MFMA(ah1, bh1, acc);
            acc = MFMA(ah0, bl0, acc);
            acc = MFMA(ah1, bl1, acc);
            acc = MFMA(al0, bh0, acc);
            acc = MFMA(al1, bh1, acc);
            sreg[n] = acc;          // S[u = 16w+4h+rr][t = 16n+lr]
        }
        #pragma unroll
        for (int n = 0; n < 4; ++n) {
            float pm = fmaxf(fmaxf(sreg[n][0], sreg[n][1]), fmaxf(sreg[n][2], sreg[n][3]));
            pm = fmaxf(pm, __shfl_xor(pm, 16));
            pm = fmaxf(pm, __shfl_xor(pm, 32));
            if (half == 0) red[(16 * n + lr) * 4 + w] = pm;
        }
    }
    __syncthreads();                                   // --- barrier 3

    // ---- softmax finish in registers: exp, write P~[t][u] bf16, partial sums ----
    {
        #pragma unroll
        for (int n = 0; n < 4; ++n) {
            int t = 16 * n + lr;
            float4 r4 = *(const float4*)&red[t * 4];
            float m = fmaxf(fmaxf(r4.x, r4.y), fmaxf(r4.z, r4.w));
            ushort_t hs[4];
            float ps = 0.f;
            #pragma unroll
            for (int rr = 0; rr < 4; ++rr) {
                ushort_t h = f2bf(__expf(sreg[n][rr] - m));
                ps += bf2f(h);
                hs[rr] = h;
            }
            *(uint2*)(pt + t * 72 + 16 * w + 4 * half) =
                make_uint2((uint_t)hs[0] | ((uint_t)hs[1] << 16),
                           (uint_t)hs[2] | ((uint_t)hs[3] << 16));
            ps += __shfl_xor(ps, 16);
            ps += __shfl_xor(ps, 32);
            if (half == 0) red2[t * 4 + w] = ps;
        }
    }
    __syncthreads();                                   // --- barrier 4

    // ---- G4 (m-split over o): out = VWT @ P~^T ; A=VWT(m=o), B=P~(n=t) ----
    // C: row = o = 16w+4half+rr, col = t = 16n+lr  -> direct global scalar stores
    // (each 16-lane group writes 2 contiguous 32B runs per instruction).
    {
        short8v a0 = *(short8v*)(vwt + mrow + kc0);   // VWT rows o=16w+lr, k=u
        short8v a1 = *(short8v*)(vwt + mrow + kc1);
        float* ob = out + ((size_t)b << 22);
        int base = (i * 8) * 256 + j * 8;
        float4 bo4 = *(const float4*)(b_out + 16 * w + 4 * half);
        float bov[4] = {bo4.x, bo4.y, bo4.z, bo4.w};
        #pragma unroll
        for (int n = 0; n < 4; ++n) {
            int trow = (16 * n + lr) * 72;
            short8v p0 = *(short8v*)(pt + trow + kc0);
            short8v p1 = *(short8v*)(pt + trow + kc1);
            f32x4 acc = {0.f, 0.f, 0.f, 0.f};
            acc = MFMA(a0, p0, acc);
            acc = MFMA(a1, p1, acc);
            int t = 16 * n + lr;
            float4 s4 = *(const float4*)&red2[t * 4];
            float inv = 1.0f / (s4.x + s4.y + s4.z + s4.w);
            size_t paddr = base + ((t >> 3) << 8) + (t & 7);
            #pragma unroll
            for (int rr = 0; rr < 4; ++rr) {
                int o = 16 * w + 4 * half + rr;
                ob[((size_t)o << 16) + paddr] = acc[rr] * inv + bov[rr];
            }
        }
    }
}

extern "C" void kernel_launch(void* const* d_in, const int* in_sizes, int n_in,
                              void* d_out, int out_size, void* d_ws, size_t ws_size,
                              hipStream_t stream) {
    const float* x      = (const float*)d_in[0];
    const float* w_in   = (const float*)d_in[1];
    const float* b_in   = (const float*)d_in[2];
    const float* gamma  = (const float*)d_in[3];
    const float* beta   = (const float*)d_in[4];
    const float* mean   = (const float*)d_in[5];
    const float* var    = (const float*)d_in[6];
    const float* w_mask = (const float*)d_in[7];
    const float* b_mask = (const float*)d_in[8];
    const float* w_out  = (const float*)d_in[9];
    const float* b_out  = (const float*)d_in[10];
    float* out = (float*)d_out;
    ushort_t* xbn = (ushort_t*)d_ws;   // 4*65536*64 bf16 = 33.5 MB

    hipLaunchKernelGGL(k1_pwbn_direct, dim3(4096), dim3(256), 0, stream,
                       x, w_in, b_in, gamma, beta, mean, var, xbn);
    hipLaunchKernelGGL(k2_attn_v5, dim3(4096), dim3(256), 0, stream,
                       xbn, w_mask, b_mask, w_out, b_out, out);
}